// Round 14
// baseline (379.045 us; speedup 1.0000x reference)
//
#include <hip/hip_runtime.h>
#include <hip/hip_bf16.h>
#include <math.h>

#define N_NODES 100000
#define N_EDGES 1600000
#define D_IN    256
#define D_OUT   128
#define NHEAD   4
#define CH      32
#define GN_EPS  1e-5f

#define BSHIFT  9
#define BNODES  512
#define NBUCK   196   // ceil(100000/512)

typedef __attribute__((ext_vector_type(8))) _Float16 f16x8;
typedef __attribute__((ext_vector_type(2))) _Float16 h16x2;
typedef __attribute__((ext_vector_type(4))) float f32x4;

// ---------- small helpers ----------
__device__ inline unsigned short f2h(float f) {
    union { _Float16 h; unsigned short u; } cv;
    cv.h = (_Float16)f;
    return cv.u;
}
__device__ inline unsigned int pk2h(float a, float b) {
    union { _Float16 h[2]; unsigned int u; } cv;
    cv.h[0] = (_Float16)a; cv.h[1] = (_Float16)b;
    return cv.u;
}
__device__ inline h16x2 bch2(unsigned int u) {
    union { unsigned int u; h16x2 h; } cv;
    cv.u = u;
    return cv.h;
}
__device__ inline float mishf(float x) {
    if (x > 15.0f) return x;
    float ex = __expf(x);
    float t = ex * (ex + 2.0f);
    return x * t / (t + 2.0f);
}
// async global->LDS, 16B per lane; LDS dest must be wave-uniform base + lane*16
__device__ inline void gload_lds16(const void* g, void* l) {
    __builtin_amdgcn_global_load_lds(
        (const __attribute__((address_space(1))) unsigned int*)g,
        (__attribute__((address_space(3))) unsigned int*)l,
        16, 0, 0);
}

// ---------- kernel 0: build Wt2 (f16, PRE-SWIZZLED LDS-image tiles) + bias ----
__global__ void prep_w(const float* __restrict__ Wq, const float* __restrict__ Wk,
                       const float* __restrict__ Wv, const float* __restrict__ Wsk,
                       const float* __restrict__ bq, const float* __restrict__ bk,
                       const float* __restrict__ bv, const float* __restrict__ bsk,
                       unsigned short* __restrict__ Wt2, float* __restrict__ bcat) {
    int idx = blockIdx.x * 256 + threadIdx.x;   // 512 blocks * 256 = 131072
    int k   = idx >> 9;                          // 0..255
    int col = idx & 511;
    int which = col >> 7, c = col & 127;
    const float* W = (which == 0) ? Wq : (which == 1) ? Wk : (which == 2) ? Wv : Wsk;
    int ks = k >> 5, cc = (k >> 3) & 3, j = k & 7;
    int p = cc ^ ((col >> 2) & 3);
    Wt2[(size_t)ks * 16384 + col * 32 + p * 8 + j] = f2h(W[(size_t)k * 128 + c]);
    if (idx < 512) {
        int w2 = idx >> 7, c2 = idx & 127;
        const float* b = (w2 == 0) ? bq : (w2 == 1) ? bk : (w2 == 2) ? bv : bsk;
        bcat[idx] = b[c2];
    }
}

// ---------- kernel 1: fused 4x GEMM via f16 MFMA, async B staging ---------------
// All four outputs (q,k,v,skip) stored f16 -> unified epilogue, no divergence;
// skip re-expanded to f32 by aggregate when forming out = attn + skip.
__global__ __launch_bounds__(512, 4) void gemm_mfma(
    const float* __restrict__ x, const unsigned short* __restrict__ Wt2,
    const float* __restrict__ bcat,
    unsigned short* __restrict__ qb, unsigned short* __restrict__ kb,
    unsigned short* __restrict__ vb, unsigned short* __restrict__ skipb)
{
    __shared__ unsigned short as_[2][64 * 32];   // 2 x 4 KiB
    __shared__ unsigned short bs_[2][512 * 32];  // 2 x 32 KiB
    const int tid = threadIdx.x;
    const int nb = blockIdx.x * 64;

    const int wave = tid >> 6, lane = tid & 63;
    const int lm = lane & 15, lk = lane >> 4;
    const int wr = wave >> 2, wc = wave & 3;     // wr: row half, wc: matrix

    const int srow = tid >> 3;
    const int sk4  = (tid & 7) * 4;
    float4 areg;

    auto loadA = [&](int ks) {
        areg = make_float4(0.f, 0.f, 0.f, 0.f);
        int grow = nb + srow;
        if (grow < N_NODES)
            areg = *(const float4*)(x + (size_t)grow * D_IN + ks * 32 + sk4);
    };
    auto writeA = [&](int pb) {
        int cc = sk4 >> 3;
        int p = cc ^ ((srow >> 2) & 3);
        uint2 w;
        w.x = pk2h(areg.x, areg.y);
        w.y = pk2h(areg.z, areg.w);
        *(uint2*)(as_[pb] + srow * 32 + p * 8 + (sk4 & 7)) = w;
    };
    auto stageB = [&](int ks, int pb) {
        const unsigned short* g = Wt2 + (size_t)ks * 16384;
        #pragma unroll
        for (int it = 0; it < 4; ++it) {
            int u = it * 512 + tid;              // 16B unit, lane-linear per wave
            gload_lds16(g + u * 8, bs_[pb] + u * 8);
        }
    };

    f32x4 acc[2][8] = {};

    stageB(0, 0);
    loadA(0);
    writeA(0);
    __syncthreads();

    for (int ks = 0; ks < 8; ++ks) {
        const int pb = ks & 1;
        if (ks < 7) {
            stageB(ks + 1, pb ^ 1);
            loadA(ks + 1);
        }

        f16x8 a[2], b[8];
        #pragma unroll
        for (int rf = 0; rf < 2; ++rf) {
            int row = wr * 32 + rf * 16 + lm;
            int p = lk ^ ((row >> 2) & 3);
            a[rf] = *(const f16x8*)(as_[pb] + row * 32 + p * 8);
        }
        #pragma unroll
        for (int cf = 0; cf < 8; ++cf) {
            int col = wc * 128 + cf * 16 + lm;
            int p = lk ^ ((col >> 2) & 3);
            b[cf] = *(const f16x8*)(bs_[pb] + col * 32 + p * 8);
        }
        #pragma unroll
        for (int cf = 0; cf < 8; ++cf) {
            acc[0][cf] = __builtin_amdgcn_mfma_f32_16x16x32_f16(a[0], b[cf], acc[0][cf], 0, 0, 0);
            acc[1][cf] = __builtin_amdgcn_mfma_f32_16x16x32_f16(a[1], b[cf], acc[1][cf], 0, 0, 0);
        }

        if (ks < 7) writeA(pb ^ 1);
        __syncthreads();
    }

    unsigned short* dstb = (wc == 0) ? qb : (wc == 1) ? kb : (wc == 2) ? vb : skipb;
    const float* biasp = bcat + wc * 128;
    #pragma unroll
    for (int rf = 0; rf < 2; ++rf) {
        #pragma unroll
        for (int j = 0; j < 4; ++j) {
            const int r = nb + wr * 32 + rf * 16 + lk * 4 + j;
            if (r < N_NODES) {
                #pragma unroll
                for (int cf = 0; cf < 8; ++cf) {
                    const int col = cf * 16 + lm;
                    dstb[(size_t)r * D_OUT + col] = f2h(acc[rf][cf][j] + biasp[col]);
                }
            }
        }
    }
}

// ---------- kernel 2: degree histogram ----------
__global__ void hist_kernel(const int* __restrict__ dst, int* __restrict__ deg) {
    int e = blockIdx.x * 256 + threadIdx.x;
    if (e < N_EDGES) atomicAdd(&deg[dst[e]], 1);
}

// ---------- kernels 3-5: exclusive scan of deg -> off (2-level) ----------
__global__ __launch_bounds__(256) void scan1(const int* __restrict__ deg,
                                             int* __restrict__ off,
                                             int* __restrict__ bsum) {
    __shared__ int lds[256];
    int t = threadIdx.x;
    int base = blockIdx.x * 1024 + t * 4;
    int d0 = 0, d1 = 0, d2 = 0, d3 = 0;
    if (base + 3 < N_NODES) {
        int4 dd = *(const int4*)(deg + base);
        d0 = dd.x; d1 = dd.y; d2 = dd.z; d3 = dd.w;
    } else {
        if (base     < N_NODES) d0 = deg[base];
        if (base + 1 < N_NODES) d1 = deg[base + 1];
        if (base + 2 < N_NODES) d2 = deg[base + 2];
        if (base + 3 < N_NODES) d3 = deg[base + 3];
    }
    int s = d0 + d1 + d2 + d3;
    lds[t] = s;
    __syncthreads();
    for (int d = 1; d < 256; d <<= 1) {
        int u = (t >= d) ? lds[t - d] : 0;
        __syncthreads();
        lds[t] += u;
        __syncthreads();
    }
    int excl = lds[t] - s;
    if (base     < N_NODES) off[base]     = excl;
    if (base + 1 < N_NODES) off[base + 1] = excl + d0;
    if (base + 2 < N_NODES) off[base + 2] = excl + d0 + d1;
    if (base + 3 < N_NODES) off[base + 3] = excl + d0 + d1 + d2;
    if (t == 255) bsum[blockIdx.x] = lds[255];
}

__global__ void scan2(int* __restrict__ bsum) {  // 1 block, 128 threads, 98 values
    __shared__ int lds[128];
    int t = threadIdx.x;
    int v = (t < 98) ? bsum[t] : 0;
    lds[t] = v;
    __syncthreads();
    for (int d = 1; d < 128; d <<= 1) {
        int u = (t >= d) ? lds[t - d] : 0;
        __syncthreads();
        lds[t] += u;
        __syncthreads();
    }
    if (t < 98) bsum[t] = lds[t] - v;  // exclusive
}

__global__ void scan3(int* __restrict__ off, const int* __restrict__ bsum) {
    int add = bsum[blockIdx.x];
    int base = blockIdx.x * 1024 + threadIdx.x * 4;
    #pragma unroll
    for (int j = 0; j < 4; ++j) {
        int idx = base + j;
        if (idx < N_NODES) off[idx] += add;
    }
}

// ---------- kernel 6a: init per-bucket cursors from CSR offsets ----------
__global__ void binit(const int* __restrict__ off, int* __restrict__ bcur) {
    int t = threadIdx.x;
    if (t < NBUCK) bcur[t] = off[t * BNODES];
}

// ---------- kernel 6b: phase-1 bucket scatter (edges -> bucket-contiguous) ----
// Payload packed: (src << 9) | (dst & 511) -- 26 bits, one uint per edge.
__global__ __launch_bounds__(256) void bucket1(const int* __restrict__ src,
                                               const int* __restrict__ dst,
                                               int* __restrict__ bcur,
                                               unsigned int* __restrict__ tpair) {
    __shared__ int cnt[NBUCK], base[NBUCK], cnt2[NBUCK];
    const int t = threadIdx.x;
    const int e0 = blockIdx.x * 4096;
    if (t < NBUCK) { cnt[t] = 0; cnt2[t] = 0; }
    __syncthreads();

    #pragma unroll
    for (int u = 0; u < 16; ++u) {
        int e = e0 + u * 256 + t;
        if (e < N_EDGES) atomicAdd(&cnt[dst[e] >> BSHIFT], 1);
    }
    __syncthreads();
    if (t < NBUCK && cnt[t] > 0) base[t] = atomicAdd(&bcur[t], cnt[t]);
    __syncthreads();

    #pragma unroll
    for (int u = 0; u < 16; ++u) {
        int e = e0 + u * 256 + t;
        if (e < N_EDGES) {
            int d = dst[e];
            int b = d >> BSHIFT;
            int idx = atomicAdd(&cnt2[b], 1);
            tpair[base[b] + idx] = ((unsigned int)src[e] << BSHIFT) | (unsigned int)(d & (BNODES - 1));
        }
    }
}

// ---------- kernel 6c: phase-2 exact placement within bucket (LDS cursors) ----
__global__ __launch_bounds__(256) void bucket2(const int* __restrict__ off,
                                               const unsigned int* __restrict__ tpair,
                                               int* __restrict__ ssrc) {
    __shared__ int cur[BNODES];
    const int b = blockIdx.x;
    const int t = threadIdx.x;
    const int n0 = b * BNODES;
    #pragma unroll
    for (int u = 0; u < 2; ++u) {
        int idx = n0 + u * 256 + t;
        cur[u * 256 + t] = (idx < N_NODES) ? off[idx] : 0;
    }
    __syncthreads();

    const int start = off[n0];
    const int end = (b == NBUCK - 1) ? N_EDGES : off[n0 + BNODES];
    for (int i = start + t; i < end; i += 256) {
        unsigned int pr = tpair[i];
        int q = atomicAdd(&cur[pr & (BNODES - 1)], 1);
        ssrc[q] = (int)(pr >> BSHIFT);
    }
}

// ---------- kernel 7: per-node attention + skip-add (writes out directly) ------
// One wave per node; 4 groups of 16 lanes, lane holds 8 channels (cbase=sl*8).
// Dual independent online-softmax streams per group; f16 K (fdot2) + f16 V;
// T13 defer-rescale. Final: out = attn/den + skip (f16 -> f32), no out read.
__global__ __launch_bounds__(256) void aggregate(
    const unsigned short* __restrict__ qb, const unsigned short* __restrict__ kb,
    const unsigned short* __restrict__ vb, const unsigned short* __restrict__ skipb,
    const int* __restrict__ off, const int* __restrict__ deg,
    const int* __restrict__ ssrc, float* __restrict__ out)
{
    const int wave = threadIdx.x >> 6;
    const int lane = threadIdx.x & 63;
    const int n = blockIdx.x * 4 + wave;
    const int grp = lane >> 4, sl = lane & 15;
    const int cbase = sl * 8;
    const float scale = 0.17677669529663687f;  // 1/sqrt(32)

    uint4 qw = *(const uint4*)(qb + (size_t)n * D_OUT + cbase);
    h16x2 qh0 = bch2(qw.x), qh1 = bch2(qw.y), qh2 = bch2(qw.z), qh3 = bch2(qw.w);

    const int s0 = off[n];
    const int s1 = s0 + deg[n];

    float mA = -1e30f, denA = 0.f;
    f32x4 accA0 = {0.f, 0.f, 0.f, 0.f}, accA1 = {0.f, 0.f, 0.f, 0.f};
    float mB = -1e30f, denB = 0.f;
    f32x4 accB0 = {0.f, 0.f, 0.f, 0.f}, accB1 = {0.f, 0.f, 0.f, 0.f};

    auto edgeS = [&](int i, float& m, float& den, f32x4& a0, f32x4& a1) {
        int s = ssrc[i];
        uint4 kw = *(const uint4*)(kb + (size_t)s * D_OUT + cbase);
        uint4 vw = *(const uint4*)(vb + (size_t)s * D_OUT + cbase);
        float part =
            __builtin_amdgcn_fdot2(qh0, bch2(kw.x),
            __builtin_amdgcn_fdot2(qh1, bch2(kw.y),
            __builtin_amdgcn_fdot2(qh2, bch2(kw.z),
            __builtin_amdgcn_fdot2(qh3, bch2(kw.w), 0.f, false), false), false), false);
        part += __shfl_xor(part, 1);
        part += __shfl_xor(part, 2);
        float p = part * scale;
        if (p > m) {                       // T13: rescale only on max-update
            float corr = __expf(m - p);
            den *= corr;
            a0 *= corr;
            a1 *= corr;
            m = p;
        }
        float w = __expf(p - m);
        den += w;
        h16x2 v0 = bch2(vw.x), v1 = bch2(vw.y), v2 = bch2(vw.z), v3 = bch2(vw.w);
        a0[0] += w * (float)v0.x; a0[1] += w * (float)v0.y;
        a0[2] += w * (float)v1.x; a0[3] += w * (float)v1.y;
        a1[0] += w * (float)v2.x; a1[1] += w * (float)v2.y;
        a1[2] += w * (float)v3.x; a1[3] += w * (float)v3.y;
    };

    int i = s0 + grp;
    for (; i + 4 < s1; i += 8) {
        edgeS(i,     mA, denA, accA0, accA1);
        edgeS(i + 4, mB, denB, accB0, accB1);
    }
    if (i < s1) edgeS(i, mA, denA, accA0, accA1);

    // merge stream B into A (in-lane)
    {
        float M = fmaxf(mA, mB);
        float c1 = __expf(mA - M), c2 = __expf(mB - M);
        denA = denA * c1 + denB * c2;
        accA0 = accA0 * c1 + accB0 * c2;
        accA1 = accA1 * c1 + accB1 * c2;
        mA = M;
    }

    // merge the 4 groups (lanes sl, sl+16, sl+32, sl+48 hold same channels)
    #pragma unroll
    for (int d = 16; d <= 32; d <<= 1) {
        float mo = __shfl_xor(mA, d);
        float deno = __shfl_xor(denA, d);
        float M = fmaxf(mA, mo);
        float c1 = __expf(mA - M), c2 = __expf(mo - M);
        denA = denA * c1 + deno * c2;
        #pragma unroll
        for (int j = 0; j < 4; ++j) {
            float ao = __shfl_xor(accA0[j], d);
            accA0[j] = accA0[j] * c1 + ao * c2;
        }
        #pragma unroll
        for (int j = 0; j < 4; ++j) {
            float ao = __shfl_xor(accA1[j], d);
            accA1[j] = accA1[j] * c1 + ao * c2;
        }
        mA = M;
    }

    if (grp == 0) {
        float invd = (denA > 0.f) ? 1.0f / denA : 0.f;
        size_t o = (size_t)n * D_OUT + cbase;
        uint4 sw = *(const uint4*)(skipb + o);
        h16x2 s0h = bch2(sw.x), s1h = bch2(sw.y), s2h = bch2(sw.z), s3h = bch2(sw.w);
        float4 o0, o1;
        o0.x = accA0[0] * invd + (float)s0h.x; o0.y = accA0[1] * invd + (float)s0h.y;
        o0.z = accA0[2] * invd + (float)s1h.x; o0.w = accA0[3] * invd + (float)s1h.y;
        o1.x = accA1[0] * invd + (float)s2h.x; o1.y = accA1[1] * invd + (float)s2h.y;
        o1.z = accA1[2] * invd + (float)s3h.x; o1.w = accA1[3] * invd + (float)s3h.y;
        *(float4*)(out + o) = o0;
        *(float4*)(out + o + 4) = o1;
    }
}

// ---------- kernel 8: per-channel sum / sumsq ----------
__global__ __launch_bounds__(256) void norm_reduce(const float* __restrict__ out,
                                                   float* __restrict__ sums) {
    const int total = N_NODES * D_OUT;
    const int stride = gridDim.x * 256;           // multiple of 128
    int t = threadIdx.x;
    float s = 0.f, s2 = 0.f;
    for (int i = blockIdx.x * 256 + t; i < total; i += stride) {
        float v = out[i];
        s += v; s2 += v * v;
    }
    __shared__ float ls[256], lq[256];
    ls[t] = s; lq[t] = s2;
    __syncthreads();
    if (t < 128) {
        s  = ls[t] + ls[t + 128];
        s2 = lq[t] + lq[t + 128];
        atomicAdd(&sums[t], s);
        atomicAdd(&sums[128 + t], s2);
    }
}

// ---------- kernel 9: finalize affine coefficients ----------
__global__ void finalize(const float* __restrict__ sums, const float* __restrict__ gw,
                         const float* __restrict__ gb, const float* __restrict__ gms,
                         float* __restrict__ AB) {
    int c = threadIdx.x;  // 128 threads
    const float invN = 1.0f / (float)N_NODES;
    float mean = sums[c] * invN;
    float ex2  = sums[128 + c] * invN;
    float mu = mean * gms[c];
    float var = ex2 - 2.f * mu * mean + mu * mu;
    float inv = rsqrtf(var + GN_EPS);
    float A = gw[c] * inv;
    AB[c] = A;
    AB[128 + c] = gb[c] - mu * A;
}

// ---------- kernel 10: affine + mish (in place on d_out) ----------
__global__ __launch_bounds__(256) void mish_kernel(float* __restrict__ out,
                                                   const float* __restrict__ AB) {
    int i = blockIdx.x * 256 + threadIdx.x;       // one float4 each; grid exact
    int c4 = (i << 2) & 127;
    float4 a  = *(const float4*)(AB + c4);
    float4 b  = *(const float4*)(AB + 128 + c4);
    float4 v  = *(float4*)(out + (size_t)i * 4);
    v.x = mishf(a.x * v.x + b.x);
    v.y = mishf(a.y * v.y + b.y);
    v.z = mishf(a.z * v.z + b.z);
    v.w = mishf(a.w * v.w + b.w);
    *(float4*)(out + (size_t)i * 4) = v;
}

// ---------- launch ----------
extern "C" void kernel_launch(void* const* d_in, const int* in_sizes, int n_in,
                              void* d_out, int out_size, void* d_ws, size_t ws_size,
                              hipStream_t stream) {
    (void)in_sizes; (void)n_in; (void)out_size; (void)ws_size;

    const float* x    = (const float*)d_in[0];
    const int*   ei   = (const int*)d_in[1];
    const float* Wq   = (const float*)d_in[2];
    const float* bq   = (const float*)d_in[3];
    const float* Wk   = (const float*)d_in[4];
    const float* bk   = (const float*)d_in[5];
    const float* Wv   = (const float*)d_in[6];
    const float* bv   = (const float*)d_in[7];
    const float* Wsk  = (const float*)d_in[8];
    const float* bsk  = (const float*)d_in[9];
    const float* gw   = (const float*)d_in[10];
    const float* gb   = (const float*)d_in[11];
    const float* gms  = (const float*)d_in[12];
    float* out = (float*)d_out;

    char* ws = (char*)d_ws;
    size_t o = 0;
    auto alloc = [&](size_t bytes) -> char* {
        char* p = ws + o;
        o += (bytes + 255) & ~(size_t)255;
        return p;
    };

    unsigned short* qb    = (unsigned short*)alloc((size_t)N_NODES * D_OUT * 2);
    unsigned short* kb    = (unsigned short*)alloc((size_t)N_NODES * D_OUT * 2);
    unsigned short* vb    = (unsigned short*)alloc((size_t)N_NODES * D_OUT * 2);
    unsigned short* skipb = (unsigned short*)alloc((size_t)N_NODES * D_OUT * 2);
    int* ssrc     = (int*)alloc((size_t)N_EDGES * 4);
    unsigned int* tpair = (unsigned int*)alloc((size_t)N_EDGES * 4);
    int* deg      = (int*)alloc((size_t)N_NODES * 4);
    int* off      = (int*)alloc((size_t)(N_NODES + 1) * 4);
    int* bcur     = (int*)alloc(1024);
    int* bsum     = (int*)alloc(512);
    float* sums   = (float*)alloc(1024);
    float* AB     = (float*)alloc(1024);
    unsigned short* Wt2 = (unsigned short*)alloc((size_t)512 * 256 * 2);
    float* bcat   = (float*)alloc(512 * 4);

    const int* srcp = ei;
    const int* dstp = ei + N_EDGES;

    hipMemsetAsync(deg, 0, (size_t)N_NODES * 4, stream);
    hipMemsetAsync(sums, 0, 256 * 4, stream);

    prep_w<<<512, 256, 0, stream>>>(Wq, Wk, Wv, Wsk, bq, bk, bv, bsk, Wt2, bcat);
    gemm_mfma<<<(N_NODES + 63) / 64, 512, 0, stream>>>(x, Wt2, bcat, qb, kb, vb, skipb);

    hist_kernel<<<(N_EDGES + 255) / 256, 256, 0, stream>>>(dstp, deg);
    scan1<<<98, 256, 0, stream>>>(deg, off, bsum);
    scan2<<<1, 128, 0, stream>>>(bsum);
    scan3<<<98, 256, 0, stream>>>(off, bsum);

    binit<<<1, 256, 0, stream>>>(off, bcur);
    bucket1<<<(N_EDGES + 4095) / 4096, 256, 0, stream>>>(srcp, dstp, bcur, tpair);
    bucket2<<<NBUCK, 256, 0, stream>>>(off, tpair, ssrc);

    aggregate<<<N_NODES / 4, 256, 0, stream>>>(qb, kb, vb, skipb, off, deg, ssrc, out);

    norm_reduce<<<512, 256, 0, stream>>>(out, sums);
    finalize<<<1, 128, 0, stream>>>(sums, gw, gb, gms, AB);
    mish_kernel<<<(N_NODES * D_OUT / 4) / 256, 256, 0, stream>>>(out, AB);
}

// Round 15
// 370.841 us; speedup vs baseline: 1.0221x; 1.0221x over previous
//
#include <hip/hip_runtime.h>
#include <hip/hip_bf16.h>
#include <math.h>

#define N_NODES 100000
#define N_EDGES 1600000
#define D_IN    256
#define D_OUT   128
#define NHEAD   4
#define CH      32
#define GN_EPS  1e-5f

#define BSHIFT  9
#define BNODES  512
#define NBUCK   196   // ceil(100000/512)

typedef __attribute__((ext_vector_type(8))) _Float16 f16x8;
typedef __attribute__((ext_vector_type(2))) _Float16 h16x2;
typedef __attribute__((ext_vector_type(4))) float f32x4;

// ---------- small helpers ----------
__device__ inline unsigned short f2h(float f) {
    union { _Float16 h; unsigned short u; } cv;
    cv.h = (_Float16)f;
    return cv.u;
}
__device__ inline unsigned int pk2h(float a, float b) {
    union { _Float16 h[2]; unsigned int u; } cv;
    cv.h[0] = (_Float16)a; cv.h[1] = (_Float16)b;
    return cv.u;
}
__device__ inline h16x2 bch2(unsigned int u) {
    union { unsigned int u; h16x2 h; } cv;
    cv.u = u;
    return cv.h;
}
__device__ inline float mishf(float x) {
    if (x > 15.0f) return x;
    float ex = __expf(x);
    float t = ex * (ex + 2.0f);
    return x * t / (t + 2.0f);
}
// async global->LDS, 16B per lane; LDS dest must be wave-uniform base + lane*16
__device__ inline void gload_lds16(const void* g, void* l) {
    __builtin_amdgcn_global_load_lds(
        (const __attribute__((address_space(1))) unsigned int*)g,
        (__attribute__((address_space(3))) unsigned int*)l,
        16, 0, 0);
}

// ---------- kernel 0: build Wt2 (f16, PRE-SWIZZLED LDS-image tiles) + bias ----
__global__ void prep_w(const float* __restrict__ Wq, const float* __restrict__ Wk,
                       const float* __restrict__ Wv, const float* __restrict__ Wsk,
                       const float* __restrict__ bq, const float* __restrict__ bk,
                       const float* __restrict__ bv, const float* __restrict__ bsk,
                       unsigned short* __restrict__ Wt2, float* __restrict__ bcat) {
    int idx = blockIdx.x * 256 + threadIdx.x;   // 512 blocks * 256 = 131072
    int k   = idx >> 9;                          // 0..255
    int col = idx & 511;
    int which = col >> 7, c = col & 127;
    const float* W = (which == 0) ? Wq : (which == 1) ? Wk : (which == 2) ? Wv : Wsk;
    int ks = k >> 5, cc = (k >> 3) & 3, j = k & 7;
    int p = cc ^ ((col >> 2) & 3);
    Wt2[(size_t)ks * 16384 + col * 32 + p * 8 + j] = f2h(W[(size_t)k * 128 + c]);
    if (idx < 512) {
        int w2 = idx >> 7, c2 = idx & 127;
        const float* b = (w2 == 0) ? bq : (w2 == 1) ? bk : (w2 == 2) ? bv : bsk;
        bcat[idx] = b[c2];
    }
}

// ---------- kernel 1: fused GEMM via f16 MFMA, async B staging ------------------
// grid (1563, 2), block 512 (8 waves). blockIdx.y selects matrix pair:
// 0 -> {q,k}, 1 -> {v,skip}. Block tile 64 rows x 256 cols, BK=32, 8 k-steps.
// LDS 40KB (as 2x4K + bs 2x16K) -> up to 4 blocks/CU; acc[2][4]=32 VGPR,
// __launch_bounds__(512,6) -> 24 waves/CU (1.5x r14's 16). x read twice
// (once per pair family) -- L3-resident re-read, overlapped.
// Wave (wr,wc4)=(w>>2, w&3): rows wr*32+32, cols wc4*64..+64 (one matrix each).
__global__ __launch_bounds__(512, 6) void gemm_mfma(
    const float* __restrict__ x, const unsigned short* __restrict__ Wt2,
    const float* __restrict__ bcat,
    unsigned short* __restrict__ qb, unsigned short* __restrict__ kb,
    unsigned short* __restrict__ vb, unsigned short* __restrict__ skipb)
{
    __shared__ unsigned short as_[2][64 * 32];   // 2 x 4 KiB
    __shared__ unsigned short bs_[2][256 * 32];  // 2 x 16 KiB
    const int tid = threadIdx.x;
    const int nb = blockIdx.x * 64;
    const int mpair = blockIdx.y;                // 0: q,k   1: v,skip

    const int wave = tid >> 6, lane = tid & 63;
    const int lm = lane & 15, lk = lane >> 4;
    const int wr = wave >> 2, wc4 = wave & 3;    // wr: row half, wc4: 64-col slice

    const int srow = tid >> 3;
    const int sk4  = (tid & 7) * 4;
    float4 areg;

    auto loadA = [&](int ks) {
        areg = make_float4(0.f, 0.f, 0.f, 0.f);
        int grow = nb + srow;
        if (grow < N_NODES)
            areg = *(const float4*)(x + (size_t)grow * D_IN + ks * 32 + sk4);
    };
    auto writeA = [&](int pb) {
        int cc = sk4 >> 3;
        int p = cc ^ ((srow >> 2) & 3);
        uint2 w;
        w.x = pk2h(areg.x, areg.y);
        w.y = pk2h(areg.z, areg.w);
        *(uint2*)(as_[pb] + srow * 32 + p * 8 + (sk4 & 7)) = w;
    };
    auto stageB = [&](int ks, int pb) {
        const unsigned short* g = Wt2 + (size_t)ks * 16384 + (size_t)mpair * 8192;
        #pragma unroll
        for (int it = 0; it < 2; ++it) {
            int u = it * 512 + tid;              // 16B unit, lane-linear per wave
            gload_lds16(g + u * 8, bs_[pb] + u * 8);
        }
    };

    f32x4 acc[2][4] = {};

    stageB(0, 0);
    loadA(0);
    writeA(0);
    __syncthreads();

    for (int ks = 0; ks < 8; ++ks) {
        const int pb = ks & 1;
        if (ks < 7) {
            stageB(ks + 1, pb ^ 1);
            loadA(ks + 1);
        }

        f16x8 a[2], b[4];
        #pragma unroll
        for (int rf = 0; rf < 2; ++rf) {
            int row = wr * 32 + rf * 16 + lm;
            int p = lk ^ ((row >> 2) & 3);
            a[rf] = *(const f16x8*)(as_[pb] + row * 32 + p * 8);
        }
        #pragma unroll
        for (int cf = 0; cf < 4; ++cf) {
            int col = wc4 * 64 + cf * 16 + lm;   // local col in [0,256)
            int p = lk ^ ((col >> 2) & 3);
            b[cf] = *(const f16x8*)(bs_[pb] + col * 32 + p * 8);
        }
        #pragma unroll
        for (int cf = 0; cf < 4; ++cf) {
            acc[0][cf] = __builtin_amdgcn_mfma_f32_16x16x32_f16(a[0], b[cf], acc[0][cf], 0, 0, 0);
            acc[1][cf] = __builtin_amdgcn_mfma_f32_16x16x32_f16(a[1], b[cf], acc[1][cf], 0, 0, 0);
        }

        if (ks < 7) writeA(pb ^ 1);
        __syncthreads();
    }

    // epilogue: wave's 64 cols lie in one matrix: mat = mpair*2 + (wc4>>1)
    const int mat = mpair * 2 + (wc4 >> 1);
    unsigned short* dstb = (mat == 0) ? qb : (mat == 1) ? kb : (mat == 2) ? vb : skipb;
    const int colbase = (wc4 & 1) * 64;          // within the 128-col matrix
    const float* biasp = bcat + mat * 128;
    #pragma unroll
    for (int rf = 0; rf < 2; ++rf) {
        #pragma unroll
        for (int j = 0; j < 4; ++j) {
            const int r = nb + wr * 32 + rf * 16 + lk * 4 + j;
            if (r < N_NODES) {
                #pragma unroll
                for (int cf = 0; cf < 4; ++cf) {
                    const int col = colbase + cf * 16 + lm;
                    dstb[(size_t)r * D_OUT + col] = f2h(acc[rf][cf][j] + biasp[col]);
                }
            }
        }
    }
}

// ---------- kernel 2: degree histogram ----------
__global__ void hist_kernel(const int* __restrict__ dst, int* __restrict__ deg) {
    int e = blockIdx.x * 256 + threadIdx.x;
    if (e < N_EDGES) atomicAdd(&deg[dst[e]], 1);
}

// ---------- kernels 3-5: exclusive scan of deg -> off (2-level) ----------
__global__ __launch_bounds__(256) void scan1(const int* __restrict__ deg,
                                             int* __restrict__ off,
                                             int* __restrict__ bsum) {
    __shared__ int lds[256];
    int t = threadIdx.x;
    int base = blockIdx.x * 1024 + t * 4;
    int d0 = 0, d1 = 0, d2 = 0, d3 = 0;
    if (base + 3 < N_NODES) {
        int4 dd = *(const int4*)(deg + base);
        d0 = dd.x; d1 = dd.y; d2 = dd.z; d3 = dd.w;
    } else {
        if (base     < N_NODES) d0 = deg[base];
        if (base + 1 < N_NODES) d1 = deg[base + 1];
        if (base + 2 < N_NODES) d2 = deg[base + 2];
        if (base + 3 < N_NODES) d3 = deg[base + 3];
    }
    int s = d0 + d1 + d2 + d3;
    lds[t] = s;
    __syncthreads();
    for (int d = 1; d < 256; d <<= 1) {
        int u = (t >= d) ? lds[t - d] : 0;
        __syncthreads();
        lds[t] += u;
        __syncthreads();
    }
    int excl = lds[t] - s;
    if (base     < N_NODES) off[base]     = excl;
    if (base + 1 < N_NODES) off[base + 1] = excl + d0;
    if (base + 2 < N_NODES) off[base + 2] = excl + d0 + d1;
    if (base + 3 < N_NODES) off[base + 3] = excl + d0 + d1 + d2;
    if (t == 255) bsum[blockIdx.x] = lds[255];
}

__global__ void scan2(int* __restrict__ bsum) {  // 1 block, 128 threads, 98 values
    __shared__ int lds[128];
    int t = threadIdx.x;
    int v = (t < 98) ? bsum[t] : 0;
    lds[t] = v;
    __syncthreads();
    for (int d = 1; d < 128; d <<= 1) {
        int u = (t >= d) ? lds[t - d] : 0;
        __syncthreads();
        lds[t] += u;
        __syncthreads();
    }
    if (t < 98) bsum[t] = lds[t] - v;  // exclusive
}

__global__ void scan3(int* __restrict__ off, const int* __restrict__ bsum) {
    int add = bsum[blockIdx.x];
    int base = blockIdx.x * 1024 + threadIdx.x * 4;
    #pragma unroll
    for (int j = 0; j < 4; ++j) {
        int idx = base + j;
        if (idx < N_NODES) off[idx] += add;
    }
}

// ---------- kernel 6a: init per-bucket cursors from CSR offsets ----------
__global__ void binit(const int* __restrict__ off, int* __restrict__ bcur) {
    int t = threadIdx.x;
    if (t < NBUCK) bcur[t] = off[t * BNODES];
}

// ---------- kernel 6b: phase-1 bucket scatter (edges -> bucket-contiguous) ----
// Payload packed: (src << 9) | (dst & 511) -- 26 bits, one uint per edge.
__global__ __launch_bounds__(256) void bucket1(const int* __restrict__ src,
                                               const int* __restrict__ dst,
                                               int* __restrict__ bcur,
                                               unsigned int* __restrict__ tpair) {
    __shared__ int cnt[NBUCK], base[NBUCK], cnt2[NBUCK];
    const int t = threadIdx.x;
    const int e0 = blockIdx.x * 4096;
    if (t < NBUCK) { cnt[t] = 0; cnt2[t] = 0; }
    __syncthreads();

    #pragma unroll
    for (int u = 0; u < 16; ++u) {
        int e = e0 + u * 256 + t;
        if (e < N_EDGES) atomicAdd(&cnt[dst[e] >> BSHIFT], 1);
    }
    __syncthreads();
    if (t < NBUCK && cnt[t] > 0) base[t] = atomicAdd(&bcur[t], cnt[t]);
    __syncthreads();

    #pragma unroll
    for (int u = 0; u < 16; ++u) {
        int e = e0 + u * 256 + t;
        if (e < N_EDGES) {
            int d = dst[e];
            int b = d >> BSHIFT;
            int idx = atomicAdd(&cnt2[b], 1);
            tpair[base[b] + idx] = ((unsigned int)src[e] << BSHIFT) | (unsigned int)(d & (BNODES - 1));
        }
    }
}

// ---------- kernel 6c: phase-2 exact placement within bucket (LDS cursors) ----
__global__ __launch_bounds__(256) void bucket2(const int* __restrict__ off,
                                               const unsigned int* __restrict__ tpair,
                                               int* __restrict__ ssrc) {
    __shared__ int cur[BNODES];
    const int b = blockIdx.x;
    const int t = threadIdx.x;
    const int n0 = b * BNODES;
    #pragma unroll
    for (int u = 0; u < 2; ++u) {
        int idx = n0 + u * 256 + t;
        cur[u * 256 + t] = (idx < N_NODES) ? off[idx] : 0;
    }
    __syncthreads();

    const int start = off[n0];
    const int end = (b == NBUCK - 1) ? N_EDGES : off[n0 + BNODES];
    for (int i = start + t; i < end; i += 256) {
        unsigned int pr = tpair[i];
        int q = atomicAdd(&cur[pr & (BNODES - 1)], 1);
        ssrc[q] = (int)(pr >> BSHIFT);
    }
}

// ---------- kernel 7: per-node attention + skip-add (writes out directly) ------
// One wave per node; 4 groups of 16 lanes, lane holds 8 channels (cbase=sl*8).
// Dual independent online-softmax streams per group; f16 K (fdot2) + f16 V;
// T13 defer-rescale. Final: out = attn/den + skip (f16 -> f32), no out read.
__global__ __launch_bounds__(256) void aggregate(
    const unsigned short* __restrict__ qb, const unsigned short* __restrict__ kb,
    const unsigned short* __restrict__ vb, const unsigned short* __restrict__ skipb,
    const int* __restrict__ off, const int* __restrict__ deg,
    const int* __restrict__ ssrc, float* __restrict__ out)
{
    const int wave = threadIdx.x >> 6;
    const int lane = threadIdx.x & 63;
    const int n = blockIdx.x * 4 + wave;
    const int grp = lane >> 4, sl = lane & 15;
    const int cbase = sl * 8;
    const float scale = 0.17677669529663687f;  // 1/sqrt(32)

    uint4 qw = *(const uint4*)(qb + (size_t)n * D_OUT + cbase);
    h16x2 qh0 = bch2(qw.x), qh1 = bch2(qw.y), qh2 = bch2(qw.z), qh3 = bch2(qw.w);

    const int s0 = off[n];
    const int s1 = s0 + deg[n];

    float mA = -1e30f, denA = 0.f;
    f32x4 accA0 = {0.f, 0.f, 0.f, 0.f}, accA1 = {0.f, 0.f, 0.f, 0.f};
    float mB = -1e30f, denB = 0.f;
    f32x4 accB0 = {0.f, 0.f, 0.f, 0.f}, accB1 = {0.f, 0.f, 0.f, 0.f};

    auto edgeS = [&](int i, float& m, float& den, f32x4& a0, f32x4& a1) {
        int s = ssrc[i];
        uint4 kw = *(const uint4*)(kb + (size_t)s * D_OUT + cbase);
        uint4 vw = *(const uint4*)(vb + (size_t)s * D_OUT + cbase);
        float part =
            __builtin_amdgcn_fdot2(qh0, bch2(kw.x),
            __builtin_amdgcn_fdot2(qh1, bch2(kw.y),
            __builtin_amdgcn_fdot2(qh2, bch2(kw.z),
            __builtin_amdgcn_fdot2(qh3, bch2(kw.w), 0.f, false), false), false), false);
        part += __shfl_xor(part, 1);
        part += __shfl_xor(part, 2);
        float p = part * scale;
        if (p > m) {                       // T13: rescale only on max-update
            float corr = __expf(m - p);
            den *= corr;
            a0 *= corr;
            a1 *= corr;
            m = p;
        }
        float w = __expf(p - m);
        den += w;
        h16x2 v0 = bch2(vw.x), v1 = bch2(vw.y), v2 = bch2(vw.z), v3 = bch2(vw.w);
        a0[0] += w * (float)v0.x; a0[1] += w * (float)v0.y;
        a0[2] += w * (float)v1.x; a0[3] += w * (float)v1.y;
        a1[0] += w * (float)v2.x; a1[1] += w * (float)v2.y;
        a1[2] += w * (float)v3.x; a1[3] += w * (float)v3.y;
    };

    int i = s0 + grp;
    for (; i + 4 < s1; i += 8) {
        edgeS(i,     mA, denA, accA0, accA1);
        edgeS(i + 4, mB, denB, accB0, accB1);
    }
    if (i < s1) edgeS(i, mA, denA, accA0, accA1);

    // merge stream B into A (in-lane)
    {
        float M = fmaxf(mA, mB);
        float c1 = __expf(mA - M), c2 = __expf(mB - M);
        denA = denA * c1 + denB * c2;
        accA0 = accA0 * c1 + accB0 * c2;
        accA1 = accA1 * c1 + accB1 * c2;
        mA = M;
    }

    // merge the 4 groups (lanes sl, sl+16, sl+32, sl+48 hold same channels)
    #pragma unroll
    for (int d = 16; d <= 32; d <<= 1) {
        float mo = __shfl_xor(mA, d);
        float deno = __shfl_xor(denA, d);
        float M = fmaxf(mA, mo);
        float c1 = __expf(mA - M), c2 = __expf(mo - M);
        denA = denA * c1 + deno * c2;
        #pragma unroll
        for (int j = 0; j < 4; ++j) {
            float ao = __shfl_xor(accA0[j], d);
            accA0[j] = accA0[j] * c1 + ao * c2;
        }
        #pragma unroll
        for (int j = 0; j < 4; ++j) {
            float ao = __shfl_xor(accA1[j], d);
            accA1[j] = accA1[j] * c1 + ao * c2;
        }
        mA = M;
    }

    if (grp == 0) {
        float invd = (denA > 0.f) ? 1.0f / denA : 0.f;
        size_t o = (size_t)n * D_OUT + cbase;
        uint4 sw = *(const uint4*)(skipb + o);
        h16x2 s0h = bch2(sw.x), s1h = bch2(sw.y), s2h = bch2(sw.z), s3h = bch2(sw.w);
        float4 o0, o1;
        o0.x = accA0[0] * invd + (float)s0h.x; o0.y = accA0[1] * invd + (float)s0h.y;
        o0.z = accA0[2] * invd + (float)s1h.x; o0.w = accA0[3] * invd + (float)s1h.y;
        o1.x = accA1[0] * invd + (float)s2h.x; o1.y = accA1[1] * invd + (float)s2h.y;
        o1.z = accA1[2] * invd + (float)s3h.x; o1.w = accA1[3] * invd + (float)s3h.y;
        *(float4*)(out + o) = o0;
        *(float4*)(out + o + 4) = o1;
    }
}

// ---------- kernel 8: per-channel sum / sumsq ----------
__global__ __launch_bounds__(256) void norm_reduce(const float* __restrict__ out,
                                                   float* __restrict__ sums) {
    const int total = N_NODES * D_OUT;
    const int stride = gridDim.x * 256;           // multiple of 128
    int t = threadIdx.x;
    float s = 0.f, s2 = 0.f;
    for (int i = blockIdx.x * 256 + t; i < total; i += stride) {
        float v = out[i];
        s += v; s2 += v * v;
    }
    __shared__ float ls[256], lq[256];
    ls[t] = s; lq[t] = s2;
    __syncthreads();
    if (t < 128) {
        s  = ls[t] + ls[t + 128];
        s2 = lq[t] + lq[t + 128];
        atomicAdd(&sums[t], s);
        atomicAdd(&sums[128 + t], s2);
    }
}

// ---------- kernel 9: finalize affine coefficients ----------
__global__ void finalize(const float* __restrict__ sums, const float* __restrict__ gw,
                         const float* __restrict__ gb, const float* __restrict__ gms,
                         float* __restrict__ AB) {
    int c = threadIdx.x;  // 128 threads
    const float invN = 1.0f / (float)N_NODES;
    float mean = sums[c] * invN;
    float ex2  = sums[128 + c] * invN;
    float mu = mean * gms[c];
    float var = ex2 - 2.f * mu * mean + mu * mu;
    float inv = rsqrtf(var + GN_EPS);
    float A = gw[c] * inv;
    AB[c] = A;
    AB[128 + c] = gb[c] - mu * A;
}

// ---------- kernel 10: affine + mish (in place on d_out) ----------
__global__ __launch_bounds__(256) void mish_kernel(float* __restrict__ out,
                                                   const float* __restrict__ AB) {
    int i = blockIdx.x * 256 + threadIdx.x;       // one float4 each; grid exact
    int c4 = (i << 2) & 127;
    float4 a  = *(const float4*)(AB + c4);
    float4 b  = *(const float4*)(AB + 128 + c4);
    float4 v  = *(float4*)(out + (size_t)i * 4);
    v.x = mishf(a.x * v.x + b.x);
    v.y = mishf(a.y * v.y + b.y);
    v.z = mishf(a.z * v.z + b.z);
    v.w = mishf(a.w * v.w + b.w);
    *(float4*)(out + (size_t)i * 4) = v;
}

// ---------- launch ----------
extern "C" void kernel_launch(void* const* d_in, const int* in_sizes, int n_in,
                              void* d_out, int out_size, void* d_ws, size_t ws_size,
                              hipStream_t stream) {
    (void)in_sizes; (void)n_in; (void)out_size; (void)ws_size;

    const float* x    = (const float*)d_in[0];
    const int*   ei   = (const int*)d_in[1];
    const float* Wq   = (const float*)d_in[2];
    const float* bq   = (const float*)d_in[3];
    const float* Wk   = (const float*)d_in[4];
    const float* bk   = (const float*)d_in[5];
    const float* Wv   = (const float*)d_in[6];
    const float* bv   = (const float*)d_in[7];
    const float* Wsk  = (const float*)d_in[8];
    const float* bsk  = (const float*)d_in[9];
    const float* gw   = (const float*)d_in[10];
    const float* gb   = (const float*)d_in[11];
    const float* gms  = (const float*)d_in[12];
    float* out = (float*)d_out;

    char* ws = (char*)d_ws;
    size_t o = 0;
    auto alloc = [&](size_t bytes) -> char* {
        char* p = ws + o;
        o += (bytes + 255) & ~(size_t)255;
        return p;
    };

    unsigned short* qb    = (unsigned short*)alloc((size_t)N_NODES * D_OUT * 2);
    unsigned short* kb    = (unsigned short*)alloc((size_t)N_NODES * D_OUT * 2);
    unsigned short* vb    = (unsigned short*)alloc((size_t)N_NODES * D_OUT * 2);
    unsigned short* skipb = (unsigned short*)alloc((size_t)N_NODES * D_OUT * 2);
    int* ssrc     = (int*)alloc((size_t)N_EDGES * 4);
    unsigned int* tpair = (unsigned int*)alloc((size_t)N_EDGES * 4);
    int* deg      = (int*)alloc((size_t)N_NODES * 4);
    int* off      = (int*)alloc((size_t)(N_NODES + 1) * 4);
    int* bcur     = (int*)alloc(1024);
    int* bsum     = (int*)alloc(512);
    float* sums   = (float*)alloc(1024);
    float* AB     = (float*)alloc(1024);
    unsigned short* Wt2 = (unsigned short*)alloc((size_t)512 * 256 * 2);
    float* bcat   = (float*)alloc(512 * 4);

    const int* srcp = ei;
    const int* dstp = ei + N_EDGES;

    hipMemsetAsync(deg, 0, (size_t)N_NODES * 4, stream);
    hipMemsetAsync(sums, 0, 256 * 4, stream);

    prep_w<<<512, 256, 0, stream>>>(Wq, Wk, Wv, Wsk, bq, bk, bv, bsk, Wt2, bcat);
    gemm_mfma<<<dim3((N_NODES + 63) / 64, 2), 512, 0, stream>>>(x, Wt2, bcat, qb, kb, vb, skipb);

    hist_kernel<<<(N_EDGES + 255) / 256, 256, 0, stream>>>(dstp, deg);
    scan1<<<98, 256, 0, stream>>>(deg, off, bsum);
    scan2<<<1, 128, 0, stream>>>(bsum);
    scan3<<<98, 256, 0, stream>>>(off, bsum);

    binit<<<1, 256, 0, stream>>>(off, bcur);
    bucket1<<<(N_EDGES + 4095) / 4096, 256, 0, stream>>>(srcp, dstp, bcur, tpair);
    bucket2<<<NBUCK, 256, 0, stream>>>(off, tpair, ssrc);

    aggregate<<<N_NODES / 4, 256, 0, stream>>>(qb, kb, vb, skipb, off, deg, ssrc, out);

    norm_reduce<<<512, 256, 0, stream>>>(out, sums);
    finalize<<<1, 128, 0, stream>>>(sums, gw, gb, gms, AB);
    mish_kernel<<<(N_NODES * D_OUT / 4) / 256, 256, 0, stream>>>(out, AB);
}